// Round 4
// baseline (307.862 us; speedup 1.0000x reference)
//
#include <hip/hip_runtime.h>
#include <hip/hip_bf16.h>
#include <cstdint>

#define NN 100000
#define NE 1600000
#define SCAN_BLK ((NN + 255) / 256)   // 391

using bf16x8 = __attribute__((ext_vector_type(8))) short;
using f32x4  = __attribute__((ext_vector_type(4))) float;

union BF8 { bf16x8 v; unsigned u[4]; };

__device__ __forceinline__ unsigned pk2(float lo, float hi) {
    union { __hip_bfloat162 b; unsigned u; } c;
    c.b = __float22bfloat162_rn(make_float2(lo, hi));
    return c.u;
}

// ---------------- counting-sort passes ----------------

__global__ __launch_bounds__(256) void hist_kernel(
    const int* __restrict__ eidx, int* __restrict__ cnt)
{
    int stride = gridDim.x * 256;
    for (int e = blockIdx.x * 256 + threadIdx.x; e < NE; e += stride)
        atomicAdd(&cnt[eidx[NE + e]], 1);
}

__global__ __launch_bounds__(256) void blocksum_kernel(
    const int* __restrict__ cnt, int* __restrict__ bsum)
{
    __shared__ int s[256];
    int n = blockIdx.x * 256 + threadIdx.x;
    s[threadIdx.x] = (n < NN) ? cnt[n] : 0;
    __syncthreads();
    for (int off = 128; off > 0; off >>= 1) {
        if (threadIdx.x < off) s[threadIdx.x] += s[threadIdx.x + off];
        __syncthreads();
    }
    if (threadIdx.x == 0) bsum[blockIdx.x] = s[0];
}

__global__ __launch_bounds__(512) void scanb_kernel(int* __restrict__ bsum)
{
    __shared__ int s[512];
    int tid = threadIdx.x;
    int v = (tid < SCAN_BLK) ? bsum[tid] : 0;
    s[tid] = v;
    __syncthreads();
    for (int off = 1; off < 512; off <<= 1) {
        int t = (tid >= off) ? s[tid - off] : 0;
        __syncthreads();
        s[tid] += t;
        __syncthreads();
    }
    if (tid < SCAN_BLK) bsum[tid] = s[tid] - v;   // exclusive
}

// cnt -> absolute exclusive offsets (in place; becomes the scatter cursor)
__global__ __launch_bounds__(256) void scanapply_kernel(
    int* __restrict__ cnt, const int* __restrict__ bsum)
{
    __shared__ int s[256];
    int n = blockIdx.x * 256 + threadIdx.x;
    int v = (n < NN) ? cnt[n] : 0;
    s[threadIdx.x] = v;
    __syncthreads();
    for (int off = 1; off < 256; off <<= 1) {
        int t = (threadIdx.x >= off) ? s[threadIdx.x - off] : 0;
        __syncthreads();
        s[threadIdx.x] += t;
        __syncthreads();
    }
    if (n < NN) cnt[n] = bsum[blockIdx.x] + s[threadIdx.x] - v;  // exclusive
}

__global__ __launch_bounds__(256) void scatter_kernel(
    const int* __restrict__ eidx, int* __restrict__ cursor,
    unsigned long long* __restrict__ pairs)
{
    int stride = gridDim.x * 256;
    for (int e = blockIdx.x * 256 + threadIdx.x; e < NE; e += stride) {
        int src = eidx[e];
        int dst = eidx[NE + e];
        int pos = atomicAdd(&cursor[dst], 1);
        pairs[pos] = (unsigned long long)(unsigned)e
                   | ((unsigned long long)(unsigned)src << 21)
                   | ((unsigned long long)(unsigned)dst << 38);
    }
}

// ---------------- root transform ----------------

__global__ __launch_bounds__(256) void root_kernel(
    const float* __restrict__ x, const float* __restrict__ root_w,
    const float* __restrict__ root_b, float* __restrict__ out)
{
    int n = blockIdx.x * 256 + threadIdx.x;
    if (n >= NN) return;
    const float4* xp = (const float4*)(x + (size_t)n * 16);
    float4 x0 = xp[0], x1 = xp[1], x2 = xp[2], x3 = xp[3];
    float xv[16] = {x0.x,x0.y,x0.z,x0.w, x1.x,x1.y,x1.z,x1.w,
                    x2.x,x2.y,x2.z,x2.w, x3.x,x3.y,x3.z,x3.w};
    float r[16];
    #pragma unroll
    for (int o = 0; o < 16; ++o) {
        float s = root_b[o];
        #pragma unroll
        for (int i = 0; i < 16; ++i) s += xv[i] * root_w[i*16 + o];
        r[o] = s;
    }
    float4* op = (float4*)(out + (size_t)n * 16);
    op[0] = make_float4(r[0], r[1], r[2], r[3]);
    op[1] = make_float4(r[4], r[5], r[6], r[7]);
    op[2] = make_float4(r[8], r[9], r[10], r[11]);
    op[3] = make_float4(r[12], r[13], r[14], r[15]);
}

// ---------------- edge MFMA over dst-sorted CSR slots ----------------
// Wave = 16 consecutive CSR slots. After MFMA, rows sharing a dst (avg
// degree 16 -> long runs) are merged in-register before the atomic.
__global__ __launch_bounds__(256) void edge_sorted_kernel(
    const float* __restrict__ edge_attr,
    const unsigned long long* __restrict__ pairs,
    const float* __restrict__ x, const float* __restrict__ edge_w,
    const float* __restrict__ edge_b, float* __restrict__ out)
{
    const int lane = threadIdx.x & 63;
    const int row  = lane & 15;
    const int quad = lane >> 4;
    const int hi   = quad & 1;
    const int q2   = quad >> 1;

    BF8 bfrag[5];
    #pragma unroll
    for (int ks = 0; ks < 4; ++ks) {
        int d = ks * 2 + q2;
        const float4* p = (const float4*)(edge_w + d*256 + row*16 + hi*8);
        float4 w0 = p[0], w1 = p[1];
        bfrag[ks].u[0] = pk2(w0.x, w0.y);
        bfrag[ks].u[1] = pk2(w0.z, w0.w);
        bfrag[ks].u[2] = pk2(w1.x, w1.y);
        bfrag[ks].u[3] = pk2(w1.z, w1.w);
    }
    if (quad < 2) {
        const float4* p = (const float4*)(edge_b + row*16 + hi*8);
        float4 w0 = p[0], w1 = p[1];
        bfrag[4].u[0] = pk2(w0.x, w0.y);
        bfrag[4].u[1] = pk2(w0.z, w0.w);
        bfrag[4].u[2] = pk2(w1.x, w1.y);
        bfrag[4].u[3] = pk2(w1.z, w1.w);
    } else {
        bfrag[4].u[0] = bfrag[4].u[1] = bfrag[4].u[2] = bfrag[4].u[3] = 0;
    }

    const int ntiles = NE / 16;
    const int nw = gridDim.x * 4;
    int t = blockIdx.x * 4 + (threadIdx.x >> 6);
    if (t >= ntiles) return;

    // ---- prologue: stage 0 + stage 1 ----
    unsigned long long p0 = pairs[t * 16 + row];
    int t1  = t + nw;
    int tc1 = (t1 < ntiles) ? t1 : (ntiles - 1);
    unsigned long long p1 = pairs[tc1 * 16 + row];

    unsigned e0i  = (unsigned)(p0 & 0x1FFFFFu);
    unsigned src0 = (unsigned)(p0 >> 21) & 0x1FFFFu;
    float4 xa0 = *(const float4*)(x + (size_t)src0 * 16 + hi * 8);
    float4 xb0 = *(const float4*)(x + (size_t)src0 * 16 + hi * 8 + 4);
    const float* ap0 = edge_attr + (size_t)e0i * 8;
    float4 ea00 = *(const float4*)(ap0);
    float4 ea10 = *(const float4*)(ap0 + 4);

    for (;;) {
        // (1) stage-2 pair loads
        int t2  = t1 + nw;
        int tc2 = (t2 < ntiles) ? t2 : (ntiles - 1);
        unsigned long long p2 = pairs[tc2 * 16 + row];
        // (2) stage-1 payload loads
        unsigned e1i  = (unsigned)(p1 & 0x1FFFFFu);
        unsigned src1 = (unsigned)(p1 >> 21) & 0x1FFFFu;
        float4 xa1 = *(const float4*)(x + (size_t)src1 * 16 + hi * 8);
        float4 xb1 = *(const float4*)(x + (size_t)src1 * 16 + hi * 8 + 4);
        const float* ap1 = edge_attr + (size_t)e1i * 8;
        float4 ea01 = *(const float4*)(ap1);
        float4 ea11 = *(const float4*)(ap1 + 4);

        // (3) compute tile t
        float ad0 = q2 ? ea00.y : ea00.x;
        float ad1 = q2 ? ea00.w : ea00.z;
        float ad2 = q2 ? ea10.y : ea10.x;
        float ad3 = q2 ? ea10.w : ea10.z;

        f32x4 acc = {0.f, 0.f, 0.f, 0.f};
        BF8 af;
        af.u[0] = pk2(ad0*xa0.x, ad0*xa0.y);
        af.u[1] = pk2(ad0*xa0.z, ad0*xa0.w);
        af.u[2] = pk2(ad0*xb0.x, ad0*xb0.y);
        af.u[3] = pk2(ad0*xb0.z, ad0*xb0.w);
        acc = __builtin_amdgcn_mfma_f32_16x16x32_bf16(af.v, bfrag[0].v, acc, 0, 0, 0);
        af.u[0] = pk2(ad1*xa0.x, ad1*xa0.y);
        af.u[1] = pk2(ad1*xa0.z, ad1*xa0.w);
        af.u[2] = pk2(ad1*xb0.x, ad1*xb0.y);
        af.u[3] = pk2(ad1*xb0.z, ad1*xb0.w);
        acc = __builtin_amdgcn_mfma_f32_16x16x32_bf16(af.v, bfrag[1].v, acc, 0, 0, 0);
        af.u[0] = pk2(ad2*xa0.x, ad2*xa0.y);
        af.u[1] = pk2(ad2*xa0.z, ad2*xa0.w);
        af.u[2] = pk2(ad2*xb0.x, ad2*xb0.y);
        af.u[3] = pk2(ad2*xb0.z, ad2*xb0.w);
        acc = __builtin_amdgcn_mfma_f32_16x16x32_bf16(af.v, bfrag[2].v, acc, 0, 0, 0);
        af.u[0] = pk2(ad3*xa0.x, ad3*xa0.y);
        af.u[1] = pk2(ad3*xa0.z, ad3*xa0.w);
        af.u[2] = pk2(ad3*xb0.x, ad3*xb0.y);
        af.u[3] = pk2(ad3*xb0.z, ad3*xb0.w);
        acc = __builtin_amdgcn_mfma_f32_16x16x32_bf16(af.v, bfrag[3].v, acc, 0, 0, 0);
        if (quad < 2) {
            af.u[0] = pk2(xa0.x, xa0.y);
            af.u[1] = pk2(xa0.z, xa0.w);
            af.u[2] = pk2(xb0.x, xb0.y);
            af.u[3] = pk2(xb0.z, xb0.w);
        } else {
            af.u[0] = af.u[1] = af.u[2] = af.u[3] = 0;
        }
        acc = __builtin_amdgcn_mfma_f32_16x16x32_bf16(af.v, bfrag[4].v, acc, 0, 0, 0);

        // (4) segmented merge over this quad's 4 rows, then atomics.
        // Every 16-lane segment holds all 16 slots' dsts (lane j -> slot j).
        int mydst = (int)(p0 >> 38);
        int d0 = __shfl(mydst, quad * 4 + 0, 16);
        int d1 = __shfl(mydst, quad * 4 + 1, 16);
        int d2 = __shfl(mydst, quad * 4 + 2, 16);
        int d3 = __shfl(mydst, quad * 4 + 3, 16);
        {
            float v = acc[0]; int cd = d0;
            if (d1 == cd) v += acc[1];
            else { atomicAdd(out + (size_t)cd * 16 + row, v); v = acc[1]; cd = d1; }
            if (d2 == cd) v += acc[2];
            else { atomicAdd(out + (size_t)cd * 16 + row, v); v = acc[2]; cd = d2; }
            if (d3 == cd) v += acc[3];
            else { atomicAdd(out + (size_t)cd * 16 + row, v); v = acc[3]; cd = d3; }
            atomicAdd(out + (size_t)cd * 16 + row, v);
        }

        // (5) rotate
        if (t1 >= ntiles) break;
        t = t1; t1 = t2; tc1 = tc2;
        p0 = p1; p1 = p2;
        xa0 = xa1; xb0 = xb1; ea00 = ea01; ea10 = ea11;
    }
}

extern "C" void kernel_launch(void* const* d_in, const int* in_sizes, int n_in,
                              void* d_out, int out_size, void* d_ws, size_t ws_size,
                              hipStream_t stream) {
    const float* x         = (const float*)d_in[0];
    const float* edge_attr = (const float*)d_in[1];
    const float* root_w    = (const float*)d_in[2];
    const float* root_b    = (const float*)d_in[3];
    const float* edge_w    = (const float*)d_in[4];
    const float* edge_b    = (const float*)d_in[5];
    const int*   eidx      = (const int*)d_in[6];
    float* out = (float*)d_out;

    // ws layout: cursor[NN] ints | pairs[NE] u64 | bsum[SCAN_BLK] ints
    int* cursor = (int*)d_ws;
    unsigned long long* pairs = (unsigned long long*)((char*)d_ws + (size_t)NN * 4);
    int* bsum = (int*)((char*)d_ws + (size_t)NN * 4 + (size_t)NE * 8);

    hipMemsetAsync(cursor, 0, (size_t)NN * 4, stream);
    hist_kernel<<<2048, 256, 0, stream>>>(eidx, cursor);
    blocksum_kernel<<<SCAN_BLK, 256, 0, stream>>>(cursor, bsum);
    scanb_kernel<<<1, 512, 0, stream>>>(bsum);
    scanapply_kernel<<<SCAN_BLK, 256, 0, stream>>>(cursor, bsum);
    scatter_kernel<<<2048, 256, 0, stream>>>(eidx, cursor, pairs);
    root_kernel<<<(NN + 255) / 256, 256, 0, stream>>>(x, root_w, root_b, out);
    edge_sorted_kernel<<<2048, 256, 0, stream>>>(edge_attr, pairs, x, edge_w, edge_b, out);
}

// Round 6
// 107.034 us; speedup vs baseline: 2.8763x; 2.8763x over previous
//
#include <hip/hip_runtime.h>
#include <hip/hip_bf16.h>
#include <cstdint>

#define NN 100000
#define NE 1600000

using bf16x8 = __attribute__((ext_vector_type(8))) short;
using f32x4  = __attribute__((ext_vector_type(4))) float;
using fp16x2 = __attribute__((ext_vector_type(2))) __fp16;

union BF8 { bf16x8 v; unsigned u[4]; };
union H2U { fp16x2 h; unsigned u; };

__device__ __forceinline__ unsigned pk2(float lo, float hi) {
    union { __hip_bfloat162 b; unsigned u; } c;
    c.b = __float22bfloat162_rn(make_float2(lo, hi));
    return c.u;
}

// out[n][o] = root_b[o] + sum_i x[n][i]*root_w[i][o]
__global__ __launch_bounds__(256) void root_kernel(
    const float* __restrict__ x, const float* __restrict__ root_w,
    const float* __restrict__ root_b, float* __restrict__ out)
{
    int n = blockIdx.x * 256 + threadIdx.x;
    if (n >= NN) return;
    const float4* xp = (const float4*)(x + (size_t)n * 16);
    float4 x0 = xp[0], x1 = xp[1], x2 = xp[2], x3 = xp[3];
    float xv[16] = {x0.x,x0.y,x0.z,x0.w, x1.x,x1.y,x1.z,x1.w,
                    x2.x,x2.y,x2.z,x2.w, x3.x,x3.y,x3.z,x3.w};
    float r[16];
    #pragma unroll
    for (int o = 0; o < 16; ++o) {
        float s = root_b[o];
        #pragma unroll
        for (int i = 0; i < 16; ++i) s += xv[i] * root_w[i*16 + o];
        r[o] = s;
    }
    float4* op = (float4*)(out + (size_t)n * 16);
    op[0] = make_float4(r[0], r[1], r[2], r[3]);
    op[1] = make_float4(r[4], r[5], r[6], r[7]);
    op[2] = make_float4(r[8], r[9], r[10], r[11]);
    op[3] = make_float4(r[12], r[13], r[14], r[15]);
}

// out[n][2j,2j+1] += (float) acc16[n][2j,2j+1]
__global__ __launch_bounds__(256) void merge_kernel(
    const unsigned* __restrict__ acc16, float* __restrict__ out)
{
    int i = blockIdx.x * 256 + threadIdx.x;   // dword index over NN*8
    if (i >= NN * 8) return;
    H2U c; c.u = acc16[i];
    float2 o = ((float2*)out)[i];
    o.x += (float)c.h.x;
    o.y += (float)c.h.y;
    ((float2*)out)[i] = o;
}

// One wave = one 16-edge tile per iteration, 2-deep software pipeline.
// msg_tile[16e x 16o] = Z[16e x 160k] @ W2[160k x 16o]  (see R2 notes)
// Scatter goes to a zeroed f16 accumulator via global_atomic_pk_add_f16
// (2 columns per 32-bit RMW -> half the atomic-dword traffic of f32).
__global__ __launch_bounds__(256) void edge_mfma_kernel(
    const float* __restrict__ edge_attr, const int* __restrict__ eidx,
    const float* __restrict__ x, const float* __restrict__ edge_w,
    const float* __restrict__ edge_b, unsigned char* __restrict__ accw)
{
    const int lane = threadIdx.x & 63;
    const int row  = lane & 15;   // A-row (edge-in-tile) and B/D col (o)
    const int quad = lane >> 4;   // 0..3
    const int hi   = quad & 1;
    const int q2   = quad >> 1;

    // ---- constant B fragments (VGPR-resident for whole kernel) ----
    BF8 bfrag[5];
    #pragma unroll
    for (int ks = 0; ks < 4; ++ks) {
        int d = ks * 2 + q2;
        const float4* p = (const float4*)(edge_w + d*256 + row*16 + hi*8);
        float4 w0 = p[0], w1 = p[1];
        bfrag[ks].u[0] = pk2(w0.x, w0.y);
        bfrag[ks].u[1] = pk2(w0.z, w0.w);
        bfrag[ks].u[2] = pk2(w1.x, w1.y);
        bfrag[ks].u[3] = pk2(w1.z, w1.w);
    }
    if (quad < 2) {
        const float4* p = (const float4*)(edge_b + row*16 + hi*8);
        float4 w0 = p[0], w1 = p[1];
        bfrag[4].u[0] = pk2(w0.x, w0.y);
        bfrag[4].u[1] = pk2(w0.z, w0.w);
        bfrag[4].u[2] = pk2(w1.x, w1.y);
        bfrag[4].u[3] = pk2(w1.z, w1.w);
    } else {
        bfrag[4].u[0] = bfrag[4].u[1] = bfrag[4].u[2] = bfrag[4].u[3] = 0;
    }

    const int ntiles = NE / 16;
    const int nw = gridDim.x * 4;
    int t = blockIdx.x * 4 + (threadIdx.x >> 6);
    if (t >= ntiles) return;

    // ---- prologue ----
    int  src0 = eidx[t * 16 + row];
    int4 dst0 = *(const int4*)(eidx + NE + t * 16 + quad * 4);
    int t1  = t + nw;
    int tc1 = (t1 < ntiles) ? t1 : (ntiles - 1);
    int  src1 = eidx[tc1 * 16 + row];
    int4 dst1 = *(const int4*)(eidx + NE + tc1 * 16 + quad * 4);
    float4 xa0 = *(const float4*)(x + (size_t)src0 * 16 + hi * 8);
    float4 xb0 = *(const float4*)(x + (size_t)src0 * 16 + hi * 8 + 4);
    const float* ap0 = edge_attr + ((size_t)t * 16 + row) * 8;
    float4 ea00 = *(const float4*)(ap0);
    float4 ea10 = *(const float4*)(ap0 + 4);

    for (;;) {
        // (1) issue idx loads for t2
        int t2  = t1 + nw;
        int tc2 = (t2 < ntiles) ? t2 : (ntiles - 1);
        int  src2 = eidx[tc2 * 16 + row];
        int4 dst2 = *(const int4*)(eidx + NE + tc2 * 16 + quad * 4);
        // (2) issue payload loads for t1
        float4 xa1 = *(const float4*)(x + (size_t)src1 * 16 + hi * 8);
        float4 xb1 = *(const float4*)(x + (size_t)src1 * 16 + hi * 8 + 4);
        const float* ap1 = edge_attr + ((size_t)tc1 * 16 + row) * 8;
        float4 ea01 = *(const float4*)(ap1);
        float4 ea11 = *(const float4*)(ap1 + 4);

        // (3) compute tile t
        float ad0 = q2 ? ea00.y : ea00.x;
        float ad1 = q2 ? ea00.w : ea00.z;
        float ad2 = q2 ? ea10.y : ea10.x;
        float ad3 = q2 ? ea10.w : ea10.z;

        f32x4 acc = {0.f, 0.f, 0.f, 0.f};
        BF8 af;
        af.u[0] = pk2(ad0*xa0.x, ad0*xa0.y);
        af.u[1] = pk2(ad0*xa0.z, ad0*xa0.w);
        af.u[2] = pk2(ad0*xb0.x, ad0*xb0.y);
        af.u[3] = pk2(ad0*xb0.z, ad0*xb0.w);
        acc = __builtin_amdgcn_mfma_f32_16x16x32_bf16(af.v, bfrag[0].v, acc, 0, 0, 0);
        af.u[0] = pk2(ad1*xa0.x, ad1*xa0.y);
        af.u[1] = pk2(ad1*xa0.z, ad1*xa0.w);
        af.u[2] = pk2(ad1*xb0.x, ad1*xb0.y);
        af.u[3] = pk2(ad1*xb0.z, ad1*xb0.w);
        acc = __builtin_amdgcn_mfma_f32_16x16x32_bf16(af.v, bfrag[1].v, acc, 0, 0, 0);
        af.u[0] = pk2(ad2*xa0.x, ad2*xa0.y);
        af.u[1] = pk2(ad2*xa0.z, ad2*xa0.w);
        af.u[2] = pk2(ad2*xb0.x, ad2*xb0.y);
        af.u[3] = pk2(ad2*xb0.z, ad2*xb0.w);
        acc = __builtin_amdgcn_mfma_f32_16x16x32_bf16(af.v, bfrag[2].v, acc, 0, 0, 0);
        af.u[0] = pk2(ad3*xa0.x, ad3*xa0.y);
        af.u[1] = pk2(ad3*xa0.z, ad3*xa0.w);
        af.u[2] = pk2(ad3*xb0.x, ad3*xb0.y);
        af.u[3] = pk2(ad3*xb0.z, ad3*xb0.w);
        acc = __builtin_amdgcn_mfma_f32_16x16x32_bf16(af.v, bfrag[3].v, acc, 0, 0, 0);
        if (quad < 2) {
            af.u[0] = pk2(xa0.x, xa0.y);
            af.u[1] = pk2(xa0.z, xa0.w);
            af.u[2] = pk2(xb0.x, xb0.y);
            af.u[3] = pk2(xb0.z, xb0.w);
        } else {
            af.u[0] = af.u[1] = af.u[2] = af.u[3] = 0;
        }
        acc = __builtin_amdgcn_mfma_f32_16x16x32_bf16(af.v, bfrag[4].v, acc, 0, 0, 0);

        // (4) pack column pairs, pk-atomic into the f16 accumulator.
        // Even lane o holds {col o (own), col o+1 (from lane^1)}.
        {
            float p0v = __shfl_xor(acc[0], 1);
            float p1v = __shfl_xor(acc[1], 1);
            float p2v = __shfl_xor(acc[2], 1);
            float p3v = __shfl_xor(acc[3], 1);
            if ((row & 1) == 0) {
                H2U h0, h1, h2, h3;
                h0.h = __builtin_amdgcn_cvt_pkrtz(acc[0], p0v);
                h1.h = __builtin_amdgcn_cvt_pkrtz(acc[1], p1v);
                h2.h = __builtin_amdgcn_cvt_pkrtz(acc[2], p2v);
                h3.h = __builtin_amdgcn_cvt_pkrtz(acc[3], p3v);
                void* q0 = accw + (size_t)dst0.x * 32 + row * 2;
                void* q1 = accw + (size_t)dst0.y * 32 + row * 2;
                void* q2p = accw + (size_t)dst0.z * 32 + row * 2;
                void* q3 = accw + (size_t)dst0.w * 32 + row * 2;
                asm volatile("global_atomic_pk_add_f16 %0, %1, off" :: "v"(q0), "v"(h0.u) : "memory");
                asm volatile("global_atomic_pk_add_f16 %0, %1, off" :: "v"(q1), "v"(h1.u) : "memory");
                asm volatile("global_atomic_pk_add_f16 %0, %1, off" :: "v"(q2p), "v"(h2.u) : "memory");
                asm volatile("global_atomic_pk_add_f16 %0, %1, off" :: "v"(q3), "v"(h3.u) : "memory");
            }
        }

        // (5) rotate / advance
        if (t1 >= ntiles) break;
        t = t1; t1 = t2; tc1 = tc2;
        src0 = src1; dst0 = dst1;
        src1 = src2; dst1 = dst2;
        xa0 = xa1; xb0 = xb1; ea00 = ea01; ea10 = ea11;
    }
}

extern "C" void kernel_launch(void* const* d_in, const int* in_sizes, int n_in,
                              void* d_out, int out_size, void* d_ws, size_t ws_size,
                              hipStream_t stream) {
    const float* x         = (const float*)d_in[0];
    const float* edge_attr = (const float*)d_in[1];
    const float* root_w    = (const float*)d_in[2];
    const float* root_b    = (const float*)d_in[3];
    const float* edge_w    = (const float*)d_in[4];
    const float* edge_b    = (const float*)d_in[5];
    const int*   eidx      = (const int*)d_in[6];
    float* out = (float*)d_out;

    unsigned char* accw = (unsigned char*)d_ws;   // [NN][16] f16 = 3.2 MB

    (void)hipMemsetAsync(accw, 0, (size_t)NN * 32, stream);
    root_kernel<<<(NN + 255) / 256, 256, 0, stream>>>(x, root_w, root_b, out);
    edge_mfma_kernel<<<4096, 256, 0, stream>>>(edge_attr, eidx, x, edge_w, edge_b, accw);
    merge_kernel<<<(NN * 8 + 255) / 256, 256, 0, stream>>>((const unsigned*)accw, out);
}

// Round 7
// 97.645 us; speedup vs baseline: 3.1529x; 1.0962x over previous
//
#include <hip/hip_runtime.h>
#include <hip/hip_bf16.h>
#include <cstdint>

#define NN 100000
#define NE 1600000

using bf16x8 = __attribute__((ext_vector_type(8))) short;
using f32x4  = __attribute__((ext_vector_type(4))) float;

union BF8 { bf16x8 v; unsigned u[4]; };

__device__ __forceinline__ unsigned pk2(float lo, float hi) {
    union { __hip_bfloat162 b; unsigned u; } c;
    c.b = __float22bfloat162_rn(make_float2(lo, hi));
    return c.u;
}

#define FP_SCALE 65536.0f
#define FP_INV   (1.0f / 65536.0f)

// pack two Q.16 fixed-point values into one u64 addend; sign-extension of
// the low field pre-encodes the borrow, recovered exactly at decode.
__device__ __forceinline__ unsigned long long packq(float lo, float hi) {
    long long l = (long long)__float2int_rn(lo * FP_SCALE);
    long long h = (long long)__float2int_rn(hi * FP_SCALE);
    return (unsigned long long)((h << 32) + l);
}

// merge: out[n][2j,2j+1] = root(x[n])[2j,2j+1] + decode(acc[n][j])
__global__ __launch_bounds__(256) void merge_kernel(
    const unsigned long long* __restrict__ acc, const float* __restrict__ x,
    const float* __restrict__ root_w, const float* __restrict__ root_b,
    float* __restrict__ out)
{
    int i = blockIdx.x * 256 + threadIdx.x;   // over NN*8 column pairs
    if (i >= NN * 8) return;
    int n = i >> 3, j = i & 7;

    unsigned long long s = acc[i];
    int lo = (int)(unsigned)(s & 0xffffffffULL);
    int hi = (int)(unsigned)(s >> 32);
    if (lo < 0) hi += 1;                      // undo pre-encoded borrow
    float m0 = lo * FP_INV, m1 = hi * FP_INV;

    const float4* xp = (const float4*)(x + (size_t)n * 16);
    float4 x0 = xp[0], x1 = xp[1], x2 = xp[2], x3 = xp[3];
    float xv[16] = {x0.x,x0.y,x0.z,x0.w, x1.x,x1.y,x1.z,x1.w,
                    x2.x,x2.y,x2.z,x2.w, x3.x,x3.y,x3.z,x3.w};
    int c0 = 2 * j;
    float r0 = root_b[c0], r1 = root_b[c0 + 1];
    #pragma unroll
    for (int k = 0; k < 16; ++k) {
        r0 += xv[k] * root_w[k*16 + c0];
        r1 += xv[k] * root_w[k*16 + c0 + 1];
    }
    ((float2*)out)[i] = make_float2(r0 + m0, r1 + m1);
}

// One wave = one 16-edge tile per iteration, 2-deep software pipeline.
// msg_tile[16e x 16o] = Z[16e x 160k] @ W2[160k x 16o]  (see R2 notes)
// Scatter: column pairs packed as Q.16 fixed point, one u64 atomicAdd per
// pair -> 8 atomic ops/edge instead of 16 element-adds.
__global__ __launch_bounds__(256) void edge_mfma_kernel(
    const float* __restrict__ edge_attr, const int* __restrict__ eidx,
    const float* __restrict__ x, const float* __restrict__ edge_w,
    const float* __restrict__ edge_b, unsigned long long* __restrict__ accq)
{
    const int lane = threadIdx.x & 63;
    const int row  = lane & 15;   // A-row (edge-in-tile) and B/D col (o)
    const int quad = lane >> 4;   // 0..3
    const int hi   = quad & 1;
    const int q2   = quad >> 1;

    // ---- constant B fragments (VGPR-resident for whole kernel) ----
    BF8 bfrag[5];
    #pragma unroll
    for (int ks = 0; ks < 4; ++ks) {
        int d = ks * 2 + q2;
        const float4* p = (const float4*)(edge_w + d*256 + row*16 + hi*8);
        float4 w0 = p[0], w1 = p[1];
        bfrag[ks].u[0] = pk2(w0.x, w0.y);
        bfrag[ks].u[1] = pk2(w0.z, w0.w);
        bfrag[ks].u[2] = pk2(w1.x, w1.y);
        bfrag[ks].u[3] = pk2(w1.z, w1.w);
    }
    if (quad < 2) {
        const float4* p = (const float4*)(edge_b + row*16 + hi*8);
        float4 w0 = p[0], w1 = p[1];
        bfrag[4].u[0] = pk2(w0.x, w0.y);
        bfrag[4].u[1] = pk2(w0.z, w0.w);
        bfrag[4].u[2] = pk2(w1.x, w1.y);
        bfrag[4].u[3] = pk2(w1.z, w1.w);
    } else {
        bfrag[4].u[0] = bfrag[4].u[1] = bfrag[4].u[2] = bfrag[4].u[3] = 0;
    }

    const int ntiles = NE / 16;
    const int nw = gridDim.x * 4;
    int t = blockIdx.x * 4 + (threadIdx.x >> 6);
    if (t >= ntiles) return;

    // ---- prologue ----
    int  src0 = eidx[t * 16 + row];
    int4 dst0 = *(const int4*)(eidx + NE + t * 16 + quad * 4);
    int t1  = t + nw;
    int tc1 = (t1 < ntiles) ? t1 : (ntiles - 1);
    int  src1 = eidx[tc1 * 16 + row];
    int4 dst1 = *(const int4*)(eidx + NE + tc1 * 16 + quad * 4);
    float4 xa0 = *(const float4*)(x + (size_t)src0 * 16 + hi * 8);
    float4 xb0 = *(const float4*)(x + (size_t)src0 * 16 + hi * 8 + 4);
    const float* ap0 = edge_attr + ((size_t)t * 16 + row) * 8;
    float4 ea00 = *(const float4*)(ap0);
    float4 ea10 = *(const float4*)(ap0 + 4);

    for (;;) {
        // (1) issue idx loads for t2
        int t2  = t1 + nw;
        int tc2 = (t2 < ntiles) ? t2 : (ntiles - 1);
        int  src2 = eidx[tc2 * 16 + row];
        int4 dst2 = *(const int4*)(eidx + NE + tc2 * 16 + quad * 4);
        // (2) issue payload loads for t1
        float4 xa1 = *(const float4*)(x + (size_t)src1 * 16 + hi * 8);
        float4 xb1 = *(const float4*)(x + (size_t)src1 * 16 + hi * 8 + 4);
        const float* ap1 = edge_attr + ((size_t)tc1 * 16 + row) * 8;
        float4 ea01 = *(const float4*)(ap1);
        float4 ea11 = *(const float4*)(ap1 + 4);

        // (3) compute tile t
        float ad0 = q2 ? ea00.y : ea00.x;
        float ad1 = q2 ? ea00.w : ea00.z;
        float ad2 = q2 ? ea10.y : ea10.x;
        float ad3 = q2 ? ea10.w : ea10.z;

        f32x4 acc = {0.f, 0.f, 0.f, 0.f};
        BF8 af;
        af.u[0] = pk2(ad0*xa0.x, ad0*xa0.y);
        af.u[1] = pk2(ad0*xa0.z, ad0*xa0.w);
        af.u[2] = pk2(ad0*xb0.x, ad0*xb0.y);
        af.u[3] = pk2(ad0*xb0.z, ad0*xb0.w);
        acc = __builtin_amdgcn_mfma_f32_16x16x32_bf16(af.v, bfrag[0].v, acc, 0, 0, 0);
        af.u[0] = pk2(ad1*xa0.x, ad1*xa0.y);
        af.u[1] = pk2(ad1*xa0.z, ad1*xa0.w);
        af.u[2] = pk2(ad1*xb0.x, ad1*xb0.y);
        af.u[3] = pk2(ad1*xb0.z, ad1*xb0.w);
        acc = __builtin_amdgcn_mfma_f32_16x16x32_bf16(af.v, bfrag[1].v, acc, 0, 0, 0);
        af.u[0] = pk2(ad2*xa0.x, ad2*xa0.y);
        af.u[1] = pk2(ad2*xa0.z, ad2*xa0.w);
        af.u[2] = pk2(ad2*xb0.x, ad2*xb0.y);
        af.u[3] = pk2(ad2*xb0.z, ad2*xb0.w);
        acc = __builtin_amdgcn_mfma_f32_16x16x32_bf16(af.v, bfrag[2].v, acc, 0, 0, 0);
        af.u[0] = pk2(ad3*xa0.x, ad3*xa0.y);
        af.u[1] = pk2(ad3*xa0.z, ad3*xa0.w);
        af.u[2] = pk2(ad3*xb0.x, ad3*xb0.y);
        af.u[3] = pk2(ad3*xb0.z, ad3*xb0.w);
        acc = __builtin_amdgcn_mfma_f32_16x16x32_bf16(af.v, bfrag[3].v, acc, 0, 0, 0);
        if (quad < 2) {
            af.u[0] = pk2(xa0.x, xa0.y);
            af.u[1] = pk2(xa0.z, xa0.w);
            af.u[2] = pk2(xb0.x, xb0.y);
            af.u[3] = pk2(xb0.z, xb0.w);
        } else {
            af.u[0] = af.u[1] = af.u[2] = af.u[3] = 0;
        }
        acc = __builtin_amdgcn_mfma_f32_16x16x32_bf16(af.v, bfrag[4].v, acc, 0, 0, 0);

        // (4) pack column pairs (Q.16) and u64-atomic into the accumulator.
        // Even lane o holds {col o (lo), col o+1 (hi, from lane^1)}.
        {
            float p0v = __shfl_xor(acc[0], 1);
            float p1v = __shfl_xor(acc[1], 1);
            float p2v = __shfl_xor(acc[2], 1);
            float p3v = __shfl_xor(acc[3], 1);
            if ((row & 1) == 0) {
                int jc = row >> 1;
                unsigned long long a0 = packq(acc[0], p0v);
                unsigned long long a1 = packq(acc[1], p1v);
                unsigned long long a2 = packq(acc[2], p2v);
                unsigned long long a3 = packq(acc[3], p3v);
                atomicAdd(accq + (size_t)dst0.x * 8 + jc, a0);
                atomicAdd(accq + (size_t)dst0.y * 8 + jc, a1);
                atomicAdd(accq + (size_t)dst0.z * 8 + jc, a2);
                atomicAdd(accq + (size_t)dst0.w * 8 + jc, a3);
            }
        }

        // (5) rotate / advance
        if (t1 >= ntiles) break;
        t = t1; t1 = t2; tc1 = tc2;
        src0 = src1; dst0 = dst1;
        src1 = src2; dst1 = dst2;
        xa0 = xa1; xb0 = xb1; ea00 = ea01; ea10 = ea11;
    }
}

extern "C" void kernel_launch(void* const* d_in, const int* in_sizes, int n_in,
                              void* d_out, int out_size, void* d_ws, size_t ws_size,
                              hipStream_t stream) {
    const float* x         = (const float*)d_in[0];
    const float* edge_attr = (const float*)d_in[1];
    const float* root_w    = (const float*)d_in[2];
    const float* root_b    = (const float*)d_in[3];
    const float* edge_w    = (const float*)d_in[4];
    const float* edge_b    = (const float*)d_in[5];
    const int*   eidx      = (const int*)d_in[6];
    float* out = (float*)d_out;

    unsigned long long* accq = (unsigned long long*)d_ws;  // [NN][8] u64 = 6.4 MB

    (void)hipMemsetAsync(accq, 0, (size_t)NN * 64, stream);
    edge_mfma_kernel<<<4096, 256, 0, stream>>>(edge_attr, eidx, x, edge_w, edge_b, accq);
    merge_kernel<<<(NN * 8 + 255) / 256, 256, 0, stream>>>(accq, x, root_w, root_b, out);
}

// Round 9
// 94.620 us; speedup vs baseline: 3.2537x; 1.0320x over previous
//
#include <hip/hip_runtime.h>
#include <hip/hip_bf16.h>
#include <cstdint>

#define NN 100000
#define NE 1600000

using bf16x8 = __attribute__((ext_vector_type(8))) short;
using f32x4  = __attribute__((ext_vector_type(4))) float;

union BF8 { bf16x8 v; unsigned u[4]; };

__device__ __forceinline__ unsigned pk2(float lo, float hi) {
    union { __hip_bfloat162 b; unsigned u; } c;
    c.b = __float22bfloat162_rn(make_float2(lo, hi));
    return c.u;
}

// out[n][o] = root_b[o] + sum_i x[n][i]*root_w[i][o]
__global__ __launch_bounds__(256) void root_kernel(
    const float* __restrict__ x, const float* __restrict__ root_w,
    const float* __restrict__ root_b, float* __restrict__ out)
{
    int n = blockIdx.x * 256 + threadIdx.x;
    if (n >= NN) return;
    const float4* xp = (const float4*)(x + (size_t)n * 16);
    float4 x0 = xp[0], x1 = xp[1], x2 = xp[2], x3 = xp[3];
    float xv[16] = {x0.x,x0.y,x0.z,x0.w, x1.x,x1.y,x1.z,x1.w,
                    x2.x,x2.y,x2.z,x2.w, x3.x,x3.y,x3.z,x3.w};
    float r[16];
    #pragma unroll
    for (int o = 0; o < 16; ++o) {
        float s = root_b[o];
        #pragma unroll
        for (int i = 0; i < 16; ++i) s += xv[i] * root_w[i*16 + o];
        r[o] = s;
    }
    float4* op = (float4*)(out + (size_t)n * 16);
    op[0] = make_float4(r[0], r[1], r[2], r[3]);
    op[1] = make_float4(r[4], r[5], r[6], r[7]);
    op[2] = make_float4(r[8], r[9], r[10], r[11]);
    op[3] = make_float4(r[12], r[13], r[14], r[15]);
}

// One wave = one 16-edge tile per iteration, 2-deep software pipeline.
// msg_tile[16e x 16o] = Z[16e x 160k] @ W2[160k x 16o]  (see R2 notes)
// Read-side dedup: each x row (64B) fetched exactly once per tile via one
// dwordx4/lane; each ea tile (512B) via one float2/lane. shfl redistributes
// in-register. ea fix vs R8: shfl BOTH components, select by DEST q2.
__global__ __launch_bounds__(256) void edge_mfma_kernel(
    const float* __restrict__ edge_attr, const int* __restrict__ eidx,
    const float* __restrict__ x, const float* __restrict__ edge_w,
    const float* __restrict__ edge_b, float* __restrict__ out)
{
    const int lane = threadIdx.x & 63;
    const int row  = lane & 15;   // A-row (edge-in-tile) and B/D col (o)
    const int quad = lane >> 4;   // 0..3
    const int hi   = quad & 1;
    const int q2   = quad >> 1;

    // ---- constant B fragments (VGPR-resident for whole kernel) ----
    BF8 bfrag[5];
    #pragma unroll
    for (int ks = 0; ks < 4; ++ks) {
        int d = ks * 2 + q2;
        const float4* p = (const float4*)(edge_w + d*256 + row*16 + hi*8);
        float4 w0 = p[0], w1 = p[1];
        bfrag[ks].u[0] = pk2(w0.x, w0.y);
        bfrag[ks].u[1] = pk2(w0.z, w0.w);
        bfrag[ks].u[2] = pk2(w1.x, w1.y);
        bfrag[ks].u[3] = pk2(w1.z, w1.w);
    }
    if (quad < 2) {
        const float4* p = (const float4*)(edge_b + row*16 + hi*8);
        float4 w0 = p[0], w1 = p[1];
        bfrag[4].u[0] = pk2(w0.x, w0.y);
        bfrag[4].u[1] = pk2(w0.z, w0.w);
        bfrag[4].u[2] = pk2(w1.x, w1.y);
        bfrag[4].u[3] = pk2(w1.z, w1.w);
    } else {
        bfrag[4].u[0] = bfrag[4].u[1] = bfrag[4].u[2] = bfrag[4].u[3] = 0;
    }

    const int ntiles = NE / 16;
    const int nw = gridDim.x * 4;
    int t = blockIdx.x * 4 + (threadIdx.x >> 6);
    if (t >= ntiles) return;

    // shfl source lanes for x-redistribution (quarters 2*hi, 2*hi+1 of row)
    const int sxa = hi * 32 + row;
    const int sxb = sxa + 16;

    // ---- prologue ----
    int  src0 = eidx[t * 16 + row];
    int4 dst0 = *(const int4*)(eidx + NE + t * 16 + quad * 4);
    int t1  = t + nw;
    int tc1 = (t1 < ntiles) ? t1 : (ntiles - 1);
    int  src1 = eidx[tc1 * 16 + row];
    int4 dst1 = *(const int4*)(eidx + NE + tc1 * 16 + quad * 4);
    float4 V0 = *(const float4*)(x + (size_t)src0 * 16 + quad * 4);
    float2 E0 = *(const float2*)(edge_attr + ((size_t)t * 16 + row) * 8 + quad * 2);

    for (;;) {
        // (1) issue idx loads for t2
        int t2  = t1 + nw;
        int tc2 = (t2 < ntiles) ? t2 : (ntiles - 1);
        int  src2 = eidx[tc2 * 16 + row];
        int4 dst2 = *(const int4*)(eidx + NE + tc2 * 16 + quad * 4);
        // (2) issue payload loads for t1 (dedup'd: 1 dwordx4 + 1 float2)
        float4 V1 = *(const float4*)(x + (size_t)src1 * 16 + quad * 4);
        float2 E1 = *(const float2*)(edge_attr + ((size_t)tc1 * 16 + row) * 8 + quad * 2);

        // (3) redistribute stage-0 payload in-register
        float4 xa0, xb0;
        xa0.x = __shfl(V0.x, sxa, 64);
        xa0.y = __shfl(V0.y, sxa, 64);
        xa0.z = __shfl(V0.z, sxa, 64);
        xa0.w = __shfl(V0.w, sxa, 64);
        xb0.x = __shfl(V0.x, sxb, 64);
        xb0.y = __shfl(V0.y, sxb, 64);
        xb0.z = __shfl(V0.z, sxb, 64);
        xb0.w = __shfl(V0.w, sxb, 64);
        // ea: lane ks*16+row holds attrs {2ks, 2ks+1} of edge row; shfl both
        // halves and select with the DESTINATION lane's q2.
        float ex0 = __shfl(E0.x, row,      64);
        float ey0 = __shfl(E0.y, row,      64);
        float ex1 = __shfl(E0.x, row + 16, 64);
        float ey1 = __shfl(E0.y, row + 16, 64);
        float ex2 = __shfl(E0.x, row + 32, 64);
        float ey2 = __shfl(E0.y, row + 32, 64);
        float ex3 = __shfl(E0.x, row + 48, 64);
        float ey3 = __shfl(E0.y, row + 48, 64);
        float ad0 = q2 ? ey0 : ex0;
        float ad1 = q2 ? ey1 : ex1;
        float ad2 = q2 ? ey2 : ex2;
        float ad3 = q2 ? ey3 : ex3;

        // (4) compute tile t
        f32x4 acc = {0.f, 0.f, 0.f, 0.f};
        BF8 af;
        af.u[0] = pk2(ad0*xa0.x, ad0*xa0.y);
        af.u[1] = pk2(ad0*xa0.z, ad0*xa0.w);
        af.u[2] = pk2(ad0*xb0.x, ad0*xb0.y);
        af.u[3] = pk2(ad0*xb0.z, ad0*xb0.w);
        acc = __builtin_amdgcn_mfma_f32_16x16x32_bf16(af.v, bfrag[0].v, acc, 0, 0, 0);
        af.u[0] = pk2(ad1*xa0.x, ad1*xa0.y);
        af.u[1] = pk2(ad1*xa0.z, ad1*xa0.w);
        af.u[2] = pk2(ad1*xb0.x, ad1*xb0.y);
        af.u[3] = pk2(ad1*xb0.z, ad1*xb0.w);
        acc = __builtin_amdgcn_mfma_f32_16x16x32_bf16(af.v, bfrag[1].v, acc, 0, 0, 0);
        af.u[0] = pk2(ad2*xa0.x, ad2*xa0.y);
        af.u[1] = pk2(ad2*xa0.z, ad2*xa0.w);
        af.u[2] = pk2(ad2*xb0.x, ad2*xb0.y);
        af.u[3] = pk2(ad2*xb0.z, ad2*xb0.w);
        acc = __builtin_amdgcn_mfma_f32_16x16x32_bf16(af.v, bfrag[2].v, acc, 0, 0, 0);
        af.u[0] = pk2(ad3*xa0.x, ad3*xa0.y);
        af.u[1] = pk2(ad3*xa0.z, ad3*xa0.w);
        af.u[2] = pk2(ad3*xb0.x, ad3*xb0.y);
        af.u[3] = pk2(ad3*xb0.z, ad3*xb0.w);
        acc = __builtin_amdgcn_mfma_f32_16x16x32_bf16(af.v, bfrag[3].v, acc, 0, 0, 0);
        if (quad < 2) {
            af.u[0] = pk2(xa0.x, xa0.y);
            af.u[1] = pk2(xa0.z, xa0.w);
            af.u[2] = pk2(xb0.x, xb0.y);
            af.u[3] = pk2(xb0.z, xb0.w);
        } else {
            af.u[0] = af.u[1] = af.u[2] = af.u[3] = 0;
        }
        acc = __builtin_amdgcn_mfma_f32_16x16x32_bf16(af.v, bfrag[4].v, acc, 0, 0, 0);

        // (5) atomics for tile t (direct f32 into out)
        atomicAdd(out + (size_t)dst0.x * 16 + row, acc[0]);
        atomicAdd(out + (size_t)dst0.y * 16 + row, acc[1]);
        atomicAdd(out + (size_t)dst0.z * 16 + row, acc[2]);
        atomicAdd(out + (size_t)dst0.w * 16 + row, acc[3]);

        // (6) rotate / advance
        if (t1 >= ntiles) break;
        t = t1; t1 = t2; tc1 = tc2;
        src0 = src1; dst0 = dst1;
        src1 = src2; dst1 = dst2;
        V0 = V1; E0 = E1;
    }
}

extern "C" void kernel_launch(void* const* d_in, const int* in_sizes, int n_in,
                              void* d_out, int out_size, void* d_ws, size_t ws_size,
                              hipStream_t stream) {
    const float* x         = (const float*)d_in[0];
    const float* edge_attr = (const float*)d_in[1];
    const float* root_w    = (const float*)d_in[2];
    const float* root_b    = (const float*)d_in[3];
    const float* edge_w    = (const float*)d_in[4];
    const float* edge_b    = (const float*)d_in[5];
    const int*   eidx      = (const int*)d_in[6];
    float* out = (float*)d_out;

    root_kernel<<<(NN + 255) / 256, 256, 0, stream>>>(x, root_w, root_b, out);
    edge_mfma_kernel<<<4096, 256, 0, stream>>>(edge_attr, eidx, x, edge_w, edge_b, out);
}